// Round 7
// baseline (269.735 us; speedup 1.0000x reference)
//
#include <hip/hip_runtime.h>

#define B_ 4
#define T_ 2048
#define D_ 512
#define H_ 8
#define DK_ 64
#define TBL 4095

typedef __attribute__((ext_vector_type(4))) float f32x4;
typedef __attribute__((ext_vector_type(8))) short bf16x8;
typedef __attribute__((ext_vector_type(4))) int i32x4;
typedef unsigned int u32;

static __device__ __forceinline__ float b2f(ushort u) {
    union { float f; unsigned int i; } c;
    c.i = ((unsigned int)u) << 16;
    return c.f;
}

static __device__ __forceinline__ ushort f2b(float f) {
    union { float f; unsigned int i; } c;
    c.f = f;
    unsigned int i = c.i;
    unsigned int r = (i + 0x7fffu + ((i >> 16) & 1u)) >> 16;
    return (ushort)r;
}

// async global->LDS, 16 bytes per lane (CK-style addrspace casts; LDS dest
// must be wave-uniform-base + lane*16 linear — our layouts are).
static __device__ __forceinline__ void gload_lds16(const void* g, void* l) {
    __builtin_amdgcn_global_load_lds(
        (const __attribute__((address_space(1))) u32*)g,
        (__attribute__((address_space(3))) u32*)(u32)(unsigned long long)l,
        16, 0, 0);
}

// ---------------------------------------------------------------------------
// mask width detection: flags[0] = 0 (4-byte int/f32), 1 (1-byte), 2 (2-byte)
__global__ __launch_bounds__(64) void detect_mask_kernel(const unsigned int* __restrict__ mask,
                                                         int* __restrict__ flags) {
    int lane = threadIdx.x;
    int c2 = 0, c1 = 0;
    for (int i = lane; i < 512; i += 64) {
        unsigned int v = mask[i];
        c2 += (v == 0x3F803F80u || v == 0x00010001u) ? 1 : 0;
        c1 += (v == 0x01010101u) ? 1 : 0;
    }
#pragma unroll
    for (int m = 1; m < 64; m <<= 1) {
        c2 += __shfl_xor(c2, m);
        c1 += __shfl_xor(c1, m);
    }
    if (lane == 0) flags[0] = (c2 > 8) ? 2 : ((c1 > 8) ? 1 : 0);
}

__global__ __launch_bounds__(256) void mask_prep_kernel(const void* __restrict__ mask,
                                                        const int* __restrict__ flags,
                                                        int* __restrict__ maskw) {
    int j = blockIdx.x * 256 + threadIdx.x;   // 0..8191
    int fm = flags[0];
    int v;
    if (fm == 2)      v = (((const ushort*)mask)[j] != 0);
    else if (fm == 1) v = (((const unsigned char*)mask)[j] != 0);
    else              v = (((const int*)mask)[j] != 0);
    maskw[j] = v;
}

// ---------------------------------------------------------------------------
// weights f32 -> bf16 (4 weights, z selects)
__global__ __launch_bounds__(256) void wcvt_kernel(
    const float* __restrict__ W0, const float* __restrict__ W1,
    const float* __restrict__ W2, const float* __restrict__ W3,
    ushort* __restrict__ Wc) {
    const int z = blockIdx.z;
    const float* Ws = (z == 0) ? W0 : ((z == 1) ? W1 : ((z == 2) ? W2 : W3));
    int idx = blockIdx.x * 256 + threadIdx.x;    // 0..32767, 8 elements each
    const float* wf = Ws + idx * 8;
    f32x4 a = *(const f32x4*)(wf);
    f32x4 c = *(const f32x4*)(wf + 4);
    union { ushort u[8]; i32x4 v; } o;
#pragma unroll
    for (int j = 0; j < 4; ++j) { o.u[j] = f2b(a[j]); o.u[4 + j] = f2b(c[j]); }
    *(i32x4*)(Wc + (size_t)z * (D_ * D_) + idx * 8) = o.v;
}

// ---------------------------------------------------------------------------
// xp = bf16(x + sinusoidal_pe(t, d)); one thread per (row, dim-pair).
__global__ __launch_bounds__(256) void pe_kernel(const float* __restrict__ x,
                                                 ushort* __restrict__ xp) {
    int idx = blockIdx.x * 256 + threadIdx.x;
    int i = idx & 255;        // pair index (dims 2i, 2i+1)
    int row = idx >> 8;       // b*T + t
    int t = row & (T_ - 1);
    float div = __expf((float)i * -0.035977892f);   // exp(-(2i)*ln(1e4)/512)
    float ang = (float)t * div;
    float s = sinf(ang);
    float c = cosf(ang);
    float2 v = ((const float2*)x)[row * 256 + i];
    unsigned int o = (unsigned int)f2b(v.x + s) | ((unsigned int)f2b(v.y + c) << 16);
    *(unsigned int*)(xp + (size_t)row * D_ + 2 * i) = o;
}

// ---------------------------------------------------------------------------
// antisymmetric rel-pos bias table, PRE-SCALED by log2(e) so attention can use
// native exp2:  tbl[h][j] = log2e * 0.5 * (E[j,h] - E[4094-j,h])
__global__ __launch_bounds__(256) void bias_tbl_kernel(const float* __restrict__ E,
                                                       float* __restrict__ tbl) {
    int idx = blockIdx.x * 256 + threadIdx.x;
    if (idx >= TBL * H_) return;
    int h = idx & 7;
    int j = idx >> 3;
    tbl[(size_t)h * TBL + j] =
        0.72134752044f * (E[(size_t)j * H_ + h] - E[(size_t)(4094 - j) * H_ + h]);
}

// ---------------------------------------------------------------------------
// GEMM: C[m][n] = sum_k A[m][k] * W[n][k] + bias[n]  (bf16 in, f32 acc)
// M=8192, N=512, K=512. 128x128 tile, 4 waves. global_load_lds staging.
// OUTMODE 0: bf16 out, [b][h][t][dk] head-split (Q/K/V).
// OUTMODE 1: f32 out, row-major [m][n] (final output).
template <int OUTMODE>
__global__ __launch_bounds__(256) void gemm_bt_kernel(
    const ushort* __restrict__ A,
    const ushort* __restrict__ W0, const ushort* __restrict__ W1, const ushort* __restrict__ W2,
    const float* __restrict__ bias0, const float* __restrict__ bias1, const float* __restrict__ bias2,
    void* __restrict__ O0, void* __restrict__ O1, void* __restrict__ O2) {
    __shared__ ushort As[128 * 32];
    __shared__ ushort Bs[128 * 32];

    const int z = blockIdx.z;
    const ushort* Wp = (z == 0) ? W0 : ((z == 1) ? W1 : W2);
    const float* bp = (z == 0) ? bias0 : ((z == 1) ? bias1 : bias2);
    void* Op = (z == 0) ? O0 : ((z == 1) ? O1 : O2);

    const int n0 = blockIdx.x * 128;
    const int m0 = blockIdx.y * 128;
    const int tid = threadIdx.x;
    const int lane = tid & 63;
    const int w = tid >> 6;
    const int wr = (w >> 1) * 64;
    const int wc = (w & 1) * 64;
    const int l15 = lane & 15;
    const int lg = lane >> 4;

    f32x4 acc[4][4];
#pragma unroll
    for (int mi = 0; mi < 4; ++mi)
#pragma unroll
        for (int ni = 0; ni < 4; ++ni)
            acc[mi][ni] = (f32x4){0.f, 0.f, 0.f, 0.f};

    for (int kt = 0; kt < D_ / 32; ++kt) {
        // async stage: chunk c (16B) -> LDS linear c*16; LDS layout == r*32 + s*8
#pragma unroll
        for (int p = 0; p < 2; ++p) {
            int c = tid + p * 256;      // 0..511
            int r = c >> 2;
            int s = c & 3;
            gload_lds16(A  + (size_t)(m0 + r) * D_ + kt * 32 + s * 8, As + c * 8);
            gload_lds16(Wp + (size_t)(n0 + r) * D_ + kt * 32 + s * 8, Bs + c * 8);
        }
        __syncthreads();   // drains vmcnt (compiler emits waitcnt before barrier)

        bf16x8 af[4], bfr[4];
#pragma unroll
        for (int mi = 0; mi < 4; ++mi)
            af[mi] = *(const bf16x8*)(As + (wr + mi * 16 + l15) * 32 + lg * 8);
#pragma unroll
        for (int ni = 0; ni < 4; ++ni)
            bfr[ni] = *(const bf16x8*)(Bs + (wc + ni * 16 + l15) * 32 + lg * 8);
#pragma unroll
        for (int mi = 0; mi < 4; ++mi)
#pragma unroll
            for (int ni = 0; ni < 4; ++ni)
                acc[mi][ni] = __builtin_amdgcn_mfma_f32_16x16x32_bf16(af[mi], bfr[ni], acc[mi][ni], 0, 0, 0);
        __syncthreads();
    }

#pragma unroll
    for (int ni = 0; ni < 4; ++ni) {
        int n = n0 + wc + ni * 16 + l15;
        float bv = bp[n];
#pragma unroll
        for (int mi = 0; mi < 4; ++mi) {
#pragma unroll
            for (int i = 0; i < 4; ++i) {
                int m = m0 + wr + mi * 16 + lg * 4 + i;
                float v = acc[mi][ni][i] + bv;
                if (OUTMODE == 0) {
                    int b = m >> 11;
                    int t = m & 2047;
                    int h = n >> 6;
                    int dk = n & 63;
                    ((ushort*)Op)[(((size_t)(b * H_ + h) * T_ + t) << 6) + dk] = f2b(v);
                } else {
                    ((float*)Op)[(size_t)m * D_ + n] = v;   // f32 final output
                }
            }
        }
    }
}

// ---------------------------------------------------------------------------
// fused attention, 8 waves x 16 q-rows = 128 q-rows/block (occupancy 2 blocks
// = 16 waves/CU). Scores bounded -> plain exp2 safe; masked keys get weight 0.
__global__ __launch_bounds__(512) void attn_kernel(
    const ushort* __restrict__ Q, const ushort* __restrict__ K, const ushort* __restrict__ V,
    const int* __restrict__ maskw, const float* __restrict__ tbl,
    ushort* __restrict__ Aout) {
    __shared__ ushort Ks[64 * 64];      // [key][slot^(key&7)]
    __shared__ ushort Vs[64 * 64];      // [dk][key-slot swizzled]
    __shared__ ushort Ps[8][16 * 64];   // per-wave P
    __shared__ float biasl[2176];       // pre-scaled by log2e
    __shared__ float maskl[T_];

    const int qb = blockIdx.x;   // 0..15
    const int bh = blockIdx.y;   // 0..31
    const int b = bh >> 3;
    const int h = bh & 7;
    const int tid = threadIdx.x;  // 0..511
    const int lane = tid & 63;
    const int w = tid >> 6;       // 0..7
    const int l15 = lane & 15;
    const int lg = lane >> 4;

    const ushort* Qp = Q + (size_t)bh * T_ * DK_;
    const ushort* Kp = K + (size_t)bh * T_ * DK_;
    const ushort* Vp = V + (size_t)bh * T_ * DK_;

    for (int j = tid; j < 2176; j += 512) {
        int gj = qb * 128 + j;
        biasl[j] = (gj <= 4094) ? tbl[(size_t)h * TBL + gj] : 0.f;
    }
    for (int j = tid; j < T_; j += 512)
        maskl[j] = (maskw[b * T_ + j] != 0) ? 1.0f : 0.0f;

    const int q0 = qb * 128 + w * 16;
    bf16x8 qf[2];
#pragma unroll
    for (int kf = 0; kf < 2; ++kf)
        qf[kf] = *(const bf16x8*)(Qp + (size_t)(q0 + l15) * DK_ + kf * 32 + lg * 8);

    f32x4 acc[4];
    float rs[4];
#pragma unroll
    for (int ni = 0; ni < 4; ++ni) acc[ni] = (f32x4){0.f, 0.f, 0.f, 0.f};
#pragma unroll
    for (int i = 0; i < 4; ++i) rs[i] = 0.f;
    __syncthreads();

    for (int kt = 0; kt < T_ / 64; ++kt) {
        // stage K tile: 512 threads x 16B; linear dest, pre-swizzled source col
        {
            int r = tid >> 3;
            int sl = tid & 7;
            i32x4 kv = *(const i32x4*)(Kp + (size_t)(kt * 64 + r) * DK_ + ((sl ^ (r & 7)) * 8));
            *(i32x4*)(Ks + tid * 8) = kv;
        }
        // stage V transposed: thread -> key=tid>>3, 8 dk values
        {
            int key = tid >> 3;
            int dq = (tid & 7) * 8;
            bf16x8 v = *(const bf16x8*)(Vp + (size_t)(kt * 64 + key) * DK_ + dq);
            const ushort* pv8 = (const ushort*)&v;
#pragma unroll
            for (int j = 0; j < 8; ++j) {
                int dk = dq + j;
                Vs[dk * 64 + (((key >> 3) ^ (dk & 7)) * 8) + (key & 7)] = pv8[j];
            }
        }
        __syncthreads();

        // S = Q K^T ; P = mask * exp2(S*log2e/8 + biaspre); P -> per-wave LDS
#pragma unroll
        for (int ct = 0; ct < 4; ++ct) {
            int krow = ct * 16 + l15;
            bf16x8 kf0 = *(const bf16x8*)(Ks + krow * 64 + ((lg ^ (krow & 7)) * 8));
            bf16x8 kf1 = *(const bf16x8*)(Ks + krow * 64 + (((4 + lg) ^ (krow & 7)) * 8));
            int kg = kt * 64 + ct * 16 + l15;
            float mf = maskl[kg];
            f32x4 S = (f32x4){0.f, 0.f, 0.f, 0.f};
            S = __builtin_amdgcn_mfma_f32_16x16x32_bf16(qf[0], kf0, S, 0, 0, 0);
            S = __builtin_amdgcn_mfma_f32_16x16x32_bf16(qf[1], kf1, S, 0, 0, 0);
            int jb = w * 16 + lg * 4 - kg + 2047;
#pragma unroll
            for (int i = 0; i < 4; ++i) {
                float pv = mf * exp2f(fmaf(S[i], 0.1803368801f, biasl[jb + i]));
                rs[i] += pv;                      // f32 denominator (matches ref)
                int prow = lg * 4 + i;
                int pcol = ct * 16 + l15;
                Ps[w][prow * 64 + (((pcol >> 3) ^ (prow & 7)) * 8) + (pcol & 7)] = f2b(pv);
            }
        }

        // PV accumulate
#pragma unroll
        for (int kk = 0; kk < 2; ++kk) {
            bf16x8 pf = *(const bf16x8*)(Ps[w] + l15 * 64 + (((kk * 4 + lg) ^ (l15 & 7)) * 8));
#pragma unroll
            for (int ni = 0; ni < 4; ++ni) {
                int vrow = ni * 16 + l15;
                bf16x8 vf = *(const bf16x8*)(Vs + vrow * 64 + (((kk * 4 + lg) ^ (vrow & 7)) * 8));
                acc[ni] = __builtin_amdgcn_mfma_f32_16x16x32_bf16(pf, vf, acc[ni], 0, 0, 0);
            }
        }
        __syncthreads();
    }

#pragma unroll
    for (int i = 0; i < 4; ++i) {
        float v = rs[i];
        v += __shfl_xor(v, 1);
        v += __shfl_xor(v, 2);
        v += __shfl_xor(v, 4);
        v += __shfl_xor(v, 8);
        rs[i] = v;
    }

    // attention output in [b][t][h*64+d] (row-major for the final GEMM)
#pragma unroll
    for (int ni = 0; ni < 4; ++ni)
#pragma unroll
        for (int i = 0; i < 4; ++i) {
            int t = q0 + lg * 4 + i;
            int d = h * DK_ + ni * 16 + l15;
            Aout[(size_t)(b * T_ + t) * D_ + d] = f2b(acc[ni][i] / rs[i]);
        }
}

// ---------------------------------------------------------------------------
extern "C" void kernel_launch(void* const* d_in, const int* in_sizes, int n_in,
                              void* d_out, int out_size, void* d_ws, size_t ws_size,
                              hipStream_t stream) {
    const float* x   = (const float*)d_in[0];
    const void* mask = d_in[1];
    const float* Wq  = (const float*)d_in[2];
    const float* bq  = (const float*)d_in[3];
    const float* Wk  = (const float*)d_in[4];
    const float* bk  = (const float*)d_in[5];
    const float* Wv  = (const float*)d_in[6];
    const float* bv  = (const float*)d_in[7];
    const float* Wo  = (const float*)d_in[8];
    const float* bo  = (const float*)d_in[9];
    const float* E   = (const float*)d_in[11];
    float* out = (float*)d_out;   // reference output dtype is FLOAT32

    char* ws = (char*)d_ws;
    ushort* xp  = (ushort*)(ws);                 // 8 MB (xp, later attn out)
    ushort* Qw  = (ushort*)(ws + (8u << 20));    // 8 MB  [b][h][t][dk]
    ushort* Kw  = (ushort*)(ws + (16u << 20));   // 8 MB
    ushort* Vw  = (ushort*)(ws + (24u << 20));   // 8 MB
    float* tbl  = (float*)(ws + (32u << 20));               // 131 KB (256 KB reserved)
    ushort* Wc  = (ushort*)(ws + (32u << 20) + 262144);     // 2 MB
    int* maskw  = (int*)(ws + (34u << 20) + 262144);        // 32 KB
    int* flags  = (int*)(ws + (34u << 20) + 262144 + 32768);

    if (ws_size < (35u << 20)) return;

    detect_mask_kernel<<<1, 64, 0, stream>>>((const unsigned int*)mask, flags);
    mask_prep_kernel<<<(B_ * T_) / 256, 256, 0, stream>>>(mask, flags, maskw);
    bias_tbl_kernel<<<(TBL * H_ + 255) / 256, 256, 0, stream>>>(E, tbl);
    pe_kernel<<<B_ * T_, 256, 0, stream>>>(x, xp);

    dim3 gw(128, 1, 4);
    wcvt_kernel<<<gw, 256, 0, stream>>>(Wq, Wk, Wv, Wo, Wc);

    dim3 g1(D_ / 128, (B_ * T_) / 128, 3);
    gemm_bt_kernel<0><<<g1, 256, 0, stream>>>(xp, Wc, Wc + D_ * D_, Wc + 2 * D_ * D_,
                                              bq, bk, bv, Qw, Kw, Vw);

    dim3 g2(T_ / 128, B_ * H_, 1);
    attn_kernel<<<g2, 512, 0, stream>>>(Qw, Kw, Vw, maskw, tbl, xp);

    dim3 g3(D_ / 128, (B_ * T_) / 128, 1);
    gemm_bt_kernel<1><<<g3, 256, 0, stream>>>(xp, Wc + 3 * D_ * D_, Wc + 3 * D_ * D_, Wc + 3 * D_ * D_,
                                              bo, bo, bo, out, out, out);
}

// Round 8
// 231.741 us; speedup vs baseline: 1.1639x; 1.1639x over previous
//
#include <hip/hip_runtime.h>

#define B_ 4
#define T_ 2048
#define D_ 512
#define H_ 8
#define DK_ 64
#define TBL 4095

typedef __attribute__((ext_vector_type(4))) float f32x4;
typedef __attribute__((ext_vector_type(8))) short bf16x8;
typedef __attribute__((ext_vector_type(4))) int i32x4;
typedef unsigned int u32;

static __device__ __forceinline__ float b2f(ushort u) {
    union { float f; unsigned int i; } c;
    c.i = ((unsigned int)u) << 16;
    return c.f;
}

static __device__ __forceinline__ ushort f2b(float f) {
    union { float f; unsigned int i; } c;
    c.f = f;
    unsigned int i = c.i;
    unsigned int r = (i + 0x7fffu + ((i >> 16) & 1u)) >> 16;
    return (ushort)r;
}

// async global->LDS, 16 bytes/lane; LDS dest must be wave-uniform + lane*16.
static __device__ __forceinline__ void gload_lds16(const void* g, void* l) {
    __builtin_amdgcn_global_load_lds(
        (const __attribute__((address_space(1))) u32*)g,
        (__attribute__((address_space(3))) u32*)(u32)(unsigned long long)l,
        16, 0, 0);
}

// ---------------------------------------------------------------------------
// mask width detection: flags[0] = 0 (4-byte int/f32), 1 (1-byte), 2 (2-byte)
__global__ __launch_bounds__(64) void detect_mask_kernel(const unsigned int* __restrict__ mask,
                                                         int* __restrict__ flags) {
    int lane = threadIdx.x;
    int c2 = 0, c1 = 0;
    for (int i = lane; i < 512; i += 64) {
        unsigned int v = mask[i];
        c2 += (v == 0x3F803F80u || v == 0x00010001u) ? 1 : 0;
        c1 += (v == 0x01010101u) ? 1 : 0;
    }
#pragma unroll
    for (int m = 1; m < 64; m <<= 1) {
        c2 += __shfl_xor(c2, m);
        c1 += __shfl_xor(c1, m);
    }
    if (lane == 0) flags[0] = (c2 > 8) ? 2 : ((c1 > 8) ? 1 : 0);
}

__global__ __launch_bounds__(256) void mask_prep_kernel(const void* __restrict__ mask,
                                                        const int* __restrict__ flags,
                                                        int* __restrict__ maskw) {
    int j = blockIdx.x * 256 + threadIdx.x;   // 0..8191
    int fm = flags[0];
    int v;
    if (fm == 2)      v = (((const ushort*)mask)[j] != 0);
    else if (fm == 1) v = (((const unsigned char*)mask)[j] != 0);
    else              v = (((const int*)mask)[j] != 0);
    maskw[j] = v;
}

// ---------------------------------------------------------------------------
// weights f32 -> bf16 (4 weights, z selects)
__global__ __launch_bounds__(256) void wcvt_kernel(
    const float* __restrict__ W0, const float* __restrict__ W1,
    const float* __restrict__ W2, const float* __restrict__ W3,
    ushort* __restrict__ Wc) {
    const int z = blockIdx.z;
    const float* Ws = (z == 0) ? W0 : ((z == 1) ? W1 : ((z == 2) ? W2 : W3));
    int idx = blockIdx.x * 256 + threadIdx.x;    // 0..32767, 8 elements each
    const float* wf = Ws + idx * 8;
    f32x4 a = *(const f32x4*)(wf);
    f32x4 c = *(const f32x4*)(wf + 4);
    union { ushort u[8]; i32x4 v; } o;
#pragma unroll
    for (int j = 0; j < 4; ++j) { o.u[j] = f2b(a[j]); o.u[4 + j] = f2b(c[j]); }
    *(i32x4*)(Wc + (size_t)z * (D_ * D_) + idx * 8) = o.v;
}

// ---------------------------------------------------------------------------
// xp = bf16(x + sinusoidal_pe(t, d)); one thread per (row, dim-pair).
__global__ __launch_bounds__(256) void pe_kernel(const float* __restrict__ x,
                                                 ushort* __restrict__ xp) {
    int idx = blockIdx.x * 256 + threadIdx.x;
    int i = idx & 255;        // pair index (dims 2i, 2i+1)
    int row = idx >> 8;       // b*T + t
    int t = row & (T_ - 1);
    float div = __expf((float)i * -0.035977892f);   // exp(-(2i)*ln(1e4)/512)
    float ang = (float)t * div;
    float s = sinf(ang);
    float c = cosf(ang);
    float2 v = ((const float2*)x)[row * 256 + i];
    unsigned int o = (unsigned int)f2b(v.x + s) | ((unsigned int)f2b(v.y + c) << 16);
    *(unsigned int*)(xp + (size_t)row * D_ + 2 * i) = o;
}

// ---------------------------------------------------------------------------
// antisymmetric rel-pos bias table, PRE-SCALED by log2(e):
// tbl[h][j] = log2e * 0.5 * (E[j,h] - E[4094-j,h])
__global__ __launch_bounds__(256) void bias_tbl_kernel(const float* __restrict__ E,
                                                       float* __restrict__ tbl) {
    int idx = blockIdx.x * 256 + threadIdx.x;
    if (idx >= TBL * H_) return;
    int h = idx & 7;
    int j = idx >> 3;
    tbl[(size_t)h * TBL + j] =
        0.72134752044f * (E[(size_t)j * H_ + h] - E[(size_t)(4094 - j) * H_ + h]);
}

// ---------------------------------------------------------------------------
// GEMM: C[m][n] = sum_k A[m][k]*W[n][k] + bias[n], bf16 in, f32 acc.
// 128x128 tile, 4 waves, BK=64 with T2 XOR-swizzle:
//   LDS chunk (r, sl) holds global col-chunk sl^(r&7)  (linear gload dest,
//   inverse-swizzled source; frag read uses slot (ks*4+lg)^(l15&7)).
// OUTMODE 0: bf16 out [b][h][t][dk]. OUTMODE 1: f32 out row-major.
template <int OUTMODE>
__global__ __launch_bounds__(256) void gemm_bt_kernel(
    const ushort* __restrict__ A,
    const ushort* __restrict__ W0, const ushort* __restrict__ W1, const ushort* __restrict__ W2,
    const float* __restrict__ bias0, const float* __restrict__ bias1, const float* __restrict__ bias2,
    void* __restrict__ O0, void* __restrict__ O1, void* __restrict__ O2) {
    __shared__ ushort As[128 * 64];
    __shared__ ushort Bs[128 * 64];

    const int z = blockIdx.z;
    const ushort* Wp = (z == 0) ? W0 : ((z == 1) ? W1 : W2);
    const float* bp = (z == 0) ? bias0 : ((z == 1) ? bias1 : bias2);
    void* Op = (z == 0) ? O0 : ((z == 1) ? O1 : O2);

    const int n0 = blockIdx.x * 128;
    const int m0 = blockIdx.y * 128;
    const int tid = threadIdx.x;
    const int lane = tid & 63;
    const int w = tid >> 6;
    const int wr = (w >> 1) * 64;
    const int wc = (w & 1) * 64;
    const int l15 = lane & 15;
    const int lg = lane >> 4;

    f32x4 acc[4][4];
#pragma unroll
    for (int mi = 0; mi < 4; ++mi)
#pragma unroll
        for (int ni = 0; ni < 4; ++ni)
            acc[mi][ni] = (f32x4){0.f, 0.f, 0.f, 0.f};

    for (int kt = 0; kt < D_ / 64; ++kt) {   // 8 K-steps
#pragma unroll
        for (int p = 0; p < 4; ++p) {
            int c = tid + p * 256;           // 0..1023 chunks of 16B
            int r = c >> 3;
            int scol = ((c & 7) ^ (r & 7)) * 8;   // inverse-swizzled source col
            gload_lds16(A  + (size_t)(m0 + r) * D_ + kt * 64 + scol, As + c * 8);
            gload_lds16(Wp + (size_t)(n0 + r) * D_ + kt * 64 + scol, Bs + c * 8);
        }
        __syncthreads();

#pragma unroll
        for (int ks = 0; ks < 2; ++ks) {
            bf16x8 af[4], bfr[4];
#pragma unroll
            for (int mi = 0; mi < 4; ++mi)
                af[mi] = *(const bf16x8*)(As + (wr + mi * 16 + l15) * 64 +
                                          (((ks * 4 + lg) ^ (l15 & 7)) * 8));
#pragma unroll
            for (int ni = 0; ni < 4; ++ni)
                bfr[ni] = *(const bf16x8*)(Bs + (wc + ni * 16 + l15) * 64 +
                                           (((ks * 4 + lg) ^ (l15 & 7)) * 8));
#pragma unroll
            for (int mi = 0; mi < 4; ++mi)
#pragma unroll
                for (int ni = 0; ni < 4; ++ni)
                    acc[mi][ni] = __builtin_amdgcn_mfma_f32_16x16x32_bf16(af[mi], bfr[ni], acc[mi][ni], 0, 0, 0);
        }
        __syncthreads();
    }

#pragma unroll
    for (int ni = 0; ni < 4; ++ni) {
        int n = n0 + wc + ni * 16 + l15;
        float bv = bp[n];
#pragma unroll
        for (int mi = 0; mi < 4; ++mi) {
#pragma unroll
            for (int i = 0; i < 4; ++i) {
                int m = m0 + wr + mi * 16 + lg * 4 + i;
                float v = acc[mi][ni][i] + bv;
                if (OUTMODE == 0) {
                    int b = m >> 11;
                    int t = m & 2047;
                    int h = n >> 6;
                    int dk = n & 63;
                    ((ushort*)Op)[(((size_t)(b * H_ + h) * T_ + t) << 6) + dk] = f2b(v);
                } else {
                    ((float*)Op)[(size_t)m * D_ + n] = v;   // f32 final output
                }
            }
        }
    }
}

// ---------------------------------------------------------------------------
// fused attention: 4 waves x 16 q-rows = 64 q-rows/block, grid 32x32 = 1024
// blocks -> 4 blocks/CU (LDS 37.1 KB). Round-6 zero-conflict staging patterns.
__global__ __launch_bounds__(256) void attn_kernel(
    const ushort* __restrict__ Q, const ushort* __restrict__ K, const ushort* __restrict__ V,
    const int* __restrict__ maskw, const float* __restrict__ tbl,
    ushort* __restrict__ Aout) {
    __shared__ ushort Ks[64 * 64];      // chunk (r,s) holds K col-chunk s^(r&7)
    __shared__ ushort Vs[64 * 64];      // [dk][key] swizzled, packed-u32 writes
    __shared__ ushort Ps[4][16 * 64];   // per-wave P
    __shared__ float biasl[2112];       // pre-scaled by log2e
    __shared__ ushort maskl[T_];        // bf16 1.0/0.0

    const int qb = blockIdx.x;   // 0..31 (64 q-rows each)
    const int bh = blockIdx.y;   // 0..31
    const int b = bh >> 3;
    const int h = bh & 7;
    const int tid = threadIdx.x;
    const int lane = tid & 63;
    const int w = tid >> 6;
    const int l15 = lane & 15;
    const int lg = lane >> 4;

    const ushort* Qp = Q + (size_t)bh * T_ * DK_;
    const ushort* Kp = K + (size_t)bh * T_ * DK_;
    const ushort* Vp = V + (size_t)bh * T_ * DK_;

    for (int j = tid; j < 2112; j += 256) {
        int gj = qb * 64 + j;
        biasl[j] = (gj <= 4094) ? tbl[(size_t)h * TBL + gj] : 0.f;
    }
    for (int j = tid; j < T_; j += 256)
        maskl[j] = (maskw[b * T_ + j] != 0) ? 0x3F80 : 0;

    const int q0 = qb * 64 + w * 16;
    bf16x8 qf[2];
#pragma unroll
    for (int kf = 0; kf < 2; ++kf)
        qf[kf] = *(const bf16x8*)(Qp + (size_t)(q0 + l15) * DK_ + kf * 32 + lg * 8);

    f32x4 acc[4];
    float rs[4];
#pragma unroll
    for (int ni = 0; ni < 4; ++ni) acc[ni] = (f32x4){0.f, 0.f, 0.f, 0.f};
#pragma unroll
    for (int i = 0; i < 4; ++i) rs[i] = 0.f;
    __syncthreads();

    for (int kt = 0; kt < T_ / 64; ++kt) {
        // stage K: gload_lds, linear dest + inverse-swizzled source col
#pragma unroll
        for (int p = 0; p < 2; ++p) {
            int c = tid + p * 256;   // 0..511
            int r = c >> 3;
            int scol = ((c & 7) ^ (r & 7)) * 8;
            gload_lds16(Kp + (size_t)(kt * 64 + r) * DK_ + scol, Ks + c * 8);
        }
        // stage V transposed (round-6 packed-u32 pattern, 0 conflicts)
        {
            int p2 = lane & 31;
            int half = lane >> 5;
            int dk0 = w * 16 + half * 8;
            const ushort* src = Vp + (size_t)(kt * 64 + 2 * p2) * DK_ + dk0;
            i32x4 lo = *(const i32x4*)(src);
            i32x4 hi = *(const i32x4*)(src + DK_);
            const ushort* plo = (const ushort*)&lo;
            const ushort* phi = (const ushort*)&hi;
#pragma unroll
            for (int j = 0; j < 8; ++j) {
                int dk = dk0 + j;
                unsigned int word = (unsigned int)plo[j] | ((unsigned int)phi[j] << 16);
                int slot = p2 >> 2;
                int wi = p2 & 3;
                *(unsigned int*)(Vs + dk * 64 + ((slot ^ (dk & 7)) * 8) + wi * 2) = word;
            }
        }
        __syncthreads();

        // S = Q K^T ; P = mask * exp2(S*log2e/8 + biaspre); P -> per-wave LDS
#pragma unroll
        for (int ct = 0; ct < 4; ++ct) {
            int krow = ct * 16 + l15;
            bf16x8 kf0 = *(const bf16x8*)(Ks + krow * 64 + ((lg ^ (krow & 7)) * 8));
            bf16x8 kf1 = *(const bf16x8*)(Ks + krow * 64 + (((4 + lg) ^ (krow & 7)) * 8));
            int kg = kt * 64 + ct * 16 + l15;
            float mf = b2f(maskl[kg]);
            f32x4 S = (f32x4){0.f, 0.f, 0.f, 0.f};
            S = __builtin_amdgcn_mfma_f32_16x16x32_bf16(qf[0], kf0, S, 0, 0, 0);
            S = __builtin_amdgcn_mfma_f32_16x16x32_bf16(qf[1], kf1, S, 0, 0, 0);
            int jb = w * 16 + lg * 4 - kg + 2047;
#pragma unroll
            for (int i = 0; i < 4; ++i) {
                float pv = mf * exp2f(fmaf(S[i], 0.1803368801f, biasl[jb + i]));
                rs[i] += pv;
                int prow = lg * 4 + i;
                int pcol = ct * 16 + l15;
                Ps[w][prow * 64 + (((pcol >> 3) ^ (prow & 7)) * 8) + (pcol & 7)] = f2b(pv);
            }
        }

        // PV accumulate
#pragma unroll
        for (int kk = 0; kk < 2; ++kk) {
            bf16x8 pf = *(const bf16x8*)(Ps[w] + l15 * 64 + (((kk * 4 + lg) ^ (l15 & 7)) * 8));
#pragma unroll
            for (int ni = 0; ni < 4; ++ni) {
                int vrow = ni * 16 + l15;
                bf16x8 vf = *(const bf16x8*)(Vs + vrow * 64 + (((kk * 4 + lg) ^ (vrow & 7)) * 8));
                acc[ni] = __builtin_amdgcn_mfma_f32_16x16x32_bf16(pf, vf, acc[ni], 0, 0, 0);
            }
        }
        __syncthreads();
    }

#pragma unroll
    for (int i = 0; i < 4; ++i) {
        float v = rs[i];
        v += __shfl_xor(v, 1);
        v += __shfl_xor(v, 2);
        v += __shfl_xor(v, 4);
        v += __shfl_xor(v, 8);
        rs[i] = v;
    }

    // attention output in [b][t][h*64+d] (row-major for the final GEMM)
#pragma unroll
    for (int ni = 0; ni < 4; ++ni)
#pragma unroll
        for (int i = 0; i < 4; ++i) {
            int t = q0 + lg * 4 + i;
            int d = h * DK_ + ni * 16 + l15;
            Aout[(size_t)(b * T_ + t) * D_ + d] = f2b(acc[ni][i] / rs[i]);
        }
}

// ---------------------------------------------------------------------------
extern "C" void kernel_launch(void* const* d_in, const int* in_sizes, int n_in,
                              void* d_out, int out_size, void* d_ws, size_t ws_size,
                              hipStream_t stream) {
    const float* x   = (const float*)d_in[0];
    const void* mask = d_in[1];
    const float* Wq  = (const float*)d_in[2];
    const float* bq  = (const float*)d_in[3];
    const float* Wk  = (const float*)d_in[4];
    const float* bk  = (const float*)d_in[5];
    const float* Wv  = (const float*)d_in[6];
    const float* bv  = (const float*)d_in[7];
    const float* Wo  = (const float*)d_in[8];
    const float* bo  = (const float*)d_in[9];
    const float* E   = (const float*)d_in[11];
    float* out = (float*)d_out;   // reference output dtype is FLOAT32

    char* ws = (char*)d_ws;
    ushort* xp  = (ushort*)(ws);                 // 8 MB (xp, later attn out)
    ushort* Qw  = (ushort*)(ws + (8u << 20));    // 8 MB  [b][h][t][dk]
    ushort* Kw  = (ushort*)(ws + (16u << 20));   // 8 MB
    ushort* Vw  = (ushort*)(ws + (24u << 20));   // 8 MB
    float* tbl  = (float*)(ws + (32u << 20));               // 131 KB (256 KB reserved)
    ushort* Wc  = (ushort*)(ws + (32u << 20) + 262144);     // 2 MB
    int* maskw  = (int*)(ws + (34u << 20) + 262144);        // 32 KB
    int* flags  = (int*)(ws + (34u << 20) + 262144 + 32768);

    if (ws_size < (35u << 20)) return;

    detect_mask_kernel<<<1, 64, 0, stream>>>((const unsigned int*)mask, flags);
    mask_prep_kernel<<<(B_ * T_) / 256, 256, 0, stream>>>(mask, flags, maskw);
    bias_tbl_kernel<<<(TBL * H_ + 255) / 256, 256, 0, stream>>>(E, tbl);
    pe_kernel<<<B_ * T_, 256, 0, stream>>>(x, xp);

    dim3 gw(128, 1, 4);
    wcvt_kernel<<<gw, 256, 0, stream>>>(Wq, Wk, Wv, Wo, Wc);

    dim3 g1(D_ / 128, (B_ * T_) / 128, 3);
    gemm_bt_kernel<0><<<g1, 256, 0, stream>>>(xp, Wc, Wc + D_ * D_, Wc + 2 * D_ * D_,
                                              bq, bk, bv, Qw, Kw, Vw);

    dim3 g2(T_ / 64, B_ * H_, 1);
    attn_kernel<<<g2, 256, 0, stream>>>(Qw, Kw, Vw, maskw, tbl, xp);

    dim3 g3(D_ / 128, (B_ * T_) / 128, 1);
    gemm_bt_kernel<1><<<g3, 256, 0, stream>>>(xp, Wc + 3 * D_ * D_, Wc + 3 * D_ * D_, Wc + 3 * D_ * D_,
                                              bo, bo, bo, out, out, out);
}

// Round 9
// 231.145 us; speedup vs baseline: 1.1670x; 1.0026x over previous
//
#include <hip/hip_runtime.h>

#define B_ 4
#define T_ 2048
#define D_ 512
#define H_ 8
#define DK_ 64
#define TBL 4095

typedef __attribute__((ext_vector_type(4))) float f32x4;
typedef __attribute__((ext_vector_type(8))) short bf16x8;
typedef __attribute__((ext_vector_type(4))) int i32x4;
typedef unsigned int u32;

static __device__ __forceinline__ float b2f(ushort u) {
    union { float f; unsigned int i; } c;
    c.i = ((unsigned int)u) << 16;
    return c.f;
}

static __device__ __forceinline__ ushort f2b(float f) {
    union { float f; unsigned int i; } c;
    c.f = f;
    unsigned int i = c.i;
    unsigned int r = (i + 0x7fffu + ((i >> 16) & 1u)) >> 16;
    return (ushort)r;
}

// async global->LDS, 16 bytes/lane; LDS dest must be wave-uniform + lane*16.
static __device__ __forceinline__ void gload_lds16(const void* g, void* l) {
    __builtin_amdgcn_global_load_lds(
        (const __attribute__((address_space(1))) u32*)g,
        (__attribute__((address_space(3))) u32*)(u32)(unsigned long long)l,
        16, 0, 0);
}

// ---------------------------------------------------------------------------
// mask width detection: flags[0] = 0 (4-byte int/f32), 1 (1-byte), 2 (2-byte)
__global__ __launch_bounds__(64) void detect_mask_kernel(const unsigned int* __restrict__ mask,
                                                         int* __restrict__ flags) {
    int lane = threadIdx.x;
    int c2 = 0, c1 = 0;
    for (int i = lane; i < 512; i += 64) {
        unsigned int v = mask[i];
        c2 += (v == 0x3F803F80u || v == 0x00010001u) ? 1 : 0;
        c1 += (v == 0x01010101u) ? 1 : 0;
    }
#pragma unroll
    for (int m = 1; m < 64; m <<= 1) {
        c2 += __shfl_xor(c2, m);
        c1 += __shfl_xor(c1, m);
    }
    if (lane == 0) flags[0] = (c2 > 8) ? 2 : ((c1 > 8) ? 1 : 0);
}

__global__ __launch_bounds__(256) void mask_prep_kernel(const void* __restrict__ mask,
                                                        const int* __restrict__ flags,
                                                        int* __restrict__ maskw) {
    int j = blockIdx.x * 256 + threadIdx.x;   // 0..8191
    int fm = flags[0];
    int v;
    if (fm == 2)      v = (((const ushort*)mask)[j] != 0);
    else if (fm == 1) v = (((const unsigned char*)mask)[j] != 0);
    else              v = (((const int*)mask)[j] != 0);
    maskw[j] = v;
}

// ---------------------------------------------------------------------------
// weights f32 -> bf16 (4 weights, z selects)
__global__ __launch_bounds__(256) void wcvt_kernel(
    const float* __restrict__ W0, const float* __restrict__ W1,
    const float* __restrict__ W2, const float* __restrict__ W3,
    ushort* __restrict__ Wc) {
    const int z = blockIdx.z;
    const float* Ws = (z == 0) ? W0 : ((z == 1) ? W1 : ((z == 2) ? W2 : W3));
    int idx = blockIdx.x * 256 + threadIdx.x;    // 0..32767, 8 elements each
    const float* wf = Ws + idx * 8;
    f32x4 a = *(const f32x4*)(wf);
    f32x4 c = *(const f32x4*)(wf + 4);
    union { ushort u[8]; i32x4 v; } o;
#pragma unroll
    for (int j = 0; j < 4; ++j) { o.u[j] = f2b(a[j]); o.u[4 + j] = f2b(c[j]); }
    *(i32x4*)(Wc + (size_t)z * (D_ * D_) + idx * 8) = o.v;
}

// ---------------------------------------------------------------------------
// xp = bf16(x + sinusoidal_pe(t, d)); one thread per (row, dim-pair).
__global__ __launch_bounds__(256) void pe_kernel(const float* __restrict__ x,
                                                 ushort* __restrict__ xp) {
    int idx = blockIdx.x * 256 + threadIdx.x;
    int i = idx & 255;        // pair index (dims 2i, 2i+1)
    int row = idx >> 8;       // b*T + t
    int t = row & (T_ - 1);
    float div = __expf((float)i * -0.035977892f);   // exp(-(2i)*ln(1e4)/512)
    float ang = (float)t * div;
    float s = sinf(ang);
    float c = cosf(ang);
    float2 v = ((const float2*)x)[row * 256 + i];
    unsigned int o = (unsigned int)f2b(v.x + s) | ((unsigned int)f2b(v.y + c) << 16);
    *(unsigned int*)(xp + (size_t)row * D_ + 2 * i) = o;
}

// ---------------------------------------------------------------------------
// antisymmetric rel-pos bias table, PRE-SCALED by log2(e):
// tbl[h][j] = log2e * 0.5 * (E[j,h] - E[4094-j,h])
__global__ __launch_bounds__(256) void bias_tbl_kernel(const float* __restrict__ E,
                                                       float* __restrict__ tbl) {
    int idx = blockIdx.x * 256 + threadIdx.x;
    if (idx >= TBL * H_) return;
    int h = idx & 7;
    int j = idx >> 3;
    tbl[(size_t)h * TBL + j] =
        0.72134752044f * (E[(size_t)j * H_ + h] - E[(size_t)(4094 - j) * H_ + h]);
}

// ---------------------------------------------------------------------------
// GEMM: C[m][n] = sum_k A[m][k]*W[n][k] + bias[n], bf16 in, f32 acc.
// 128x128 tile, 4 waves, BK=64, T2 XOR-swizzled LDS.
// OUTMODE 0: bf16 out; z 0/1 (Q,K) -> [b][h][t][dk]; z 2 (V) -> [b][h][dk][t].
// OUTMODE 1: f32 out row-major (final output).
template <int OUTMODE>
__global__ __launch_bounds__(256) void gemm_bt_kernel(
    const ushort* __restrict__ A,
    const ushort* __restrict__ W0, const ushort* __restrict__ W1, const ushort* __restrict__ W2,
    const float* __restrict__ bias0, const float* __restrict__ bias1, const float* __restrict__ bias2,
    void* __restrict__ O0, void* __restrict__ O1, void* __restrict__ O2) {
    __shared__ ushort As[128 * 64];
    __shared__ ushort Bs[128 * 64];

    const int z = blockIdx.z;
    const ushort* Wp = (z == 0) ? W0 : ((z == 1) ? W1 : W2);
    const float* bp = (z == 0) ? bias0 : ((z == 1) ? bias1 : bias2);
    void* Op = (z == 0) ? O0 : ((z == 1) ? O1 : O2);

    const int n0 = blockIdx.x * 128;
    const int m0 = blockIdx.y * 128;
    const int tid = threadIdx.x;
    const int lane = tid & 63;
    const int w = tid >> 6;
    const int wr = (w >> 1) * 64;
    const int wc = (w & 1) * 64;
    const int l15 = lane & 15;
    const int lg = lane >> 4;

    f32x4 acc[4][4];
#pragma unroll
    for (int mi = 0; mi < 4; ++mi)
#pragma unroll
        for (int ni = 0; ni < 4; ++ni)
            acc[mi][ni] = (f32x4){0.f, 0.f, 0.f, 0.f};

    for (int kt = 0; kt < D_ / 64; ++kt) {   // 8 K-steps
#pragma unroll
        for (int p = 0; p < 4; ++p) {
            int c = tid + p * 256;           // 0..1023 chunks of 16B
            int r = c >> 3;
            int scol = ((c & 7) ^ (r & 7)) * 8;   // inverse-swizzled source col
            gload_lds16(A  + (size_t)(m0 + r) * D_ + kt * 64 + scol, As + c * 8);
            gload_lds16(Wp + (size_t)(n0 + r) * D_ + kt * 64 + scol, Bs + c * 8);
        }
        __syncthreads();

#pragma unroll
        for (int ks = 0; ks < 2; ++ks) {
            bf16x8 af[4], bfr[4];
#pragma unroll
            for (int mi = 0; mi < 4; ++mi)
                af[mi] = *(const bf16x8*)(As + (wr + mi * 16 + l15) * 64 +
                                          (((ks * 4 + lg) ^ (l15 & 7)) * 8));
#pragma unroll
            for (int ni = 0; ni < 4; ++ni)
                bfr[ni] = *(const bf16x8*)(Bs + (wc + ni * 16 + l15) * 64 +
                                           (((ks * 4 + lg) ^ (l15 & 7)) * 8));
#pragma unroll
            for (int mi = 0; mi < 4; ++mi)
#pragma unroll
                for (int ni = 0; ni < 4; ++ni)
                    acc[mi][ni] = __builtin_amdgcn_mfma_f32_16x16x32_bf16(af[mi], bfr[ni], acc[mi][ni], 0, 0, 0);
        }
        __syncthreads();
    }

#pragma unroll
    for (int ni = 0; ni < 4; ++ni) {
        int n = n0 + wc + ni * 16 + l15;
        float bv = bp[n];
#pragma unroll
        for (int mi = 0; mi < 4; ++mi) {
#pragma unroll
            for (int i = 0; i < 4; ++i) {
                int m = m0 + wr + mi * 16 + lg * 4 + i;
                float v = acc[mi][ni][i] + bv;
                if (OUTMODE == 0) {
                    int b = m >> 11;
                    int t = m & 2047;
                    int hh = n >> 6;
                    int dk = n & 63;
                    size_t off;
                    if (z == 2) off = ((size_t)(b * H_ + hh) * DK_ + dk) * T_ + t;   // V^T
                    else        off = (((size_t)(b * H_ + hh) * T_ + t) << 6) + dk;
                    ((ushort*)Op)[off] = f2b(v);
                } else {
                    ((float*)Op)[(size_t)m * D_ + n] = v;   // f32 final output
                }
            }
        }
    }
}

// ---------------------------------------------------------------------------
// fused attention: 8 waves x 16 q-rows = 128 q-rows/block, grid (16,32)=512
// blocks -> 2 blocks/CU, 16 waves/CU. K in [b][h][t][dk], V in [b][h][dk][t];
// both staged by gload_lds16 with inverse-swizzled source (zero staging VALU).
__global__ __launch_bounds__(512) void attn_kernel(
    const ushort* __restrict__ Q, const ushort* __restrict__ K, const ushort* __restrict__ Vt,
    const int* __restrict__ maskw, const float* __restrict__ tbl,
    ushort* __restrict__ Aout) {
    __shared__ ushort Ks[64 * 64];      // chunk (r,s) holds K[key=r] col-chunk s^(r&7)
    __shared__ ushort Vs[64 * 64];      // chunk (r,s) holds V^T[dk=r] key-chunk s^(r&7)
    __shared__ ushort Ps[8][16 * 64];   // per-wave P
    __shared__ float biasl[2176];       // pre-scaled by log2e
    __shared__ ushort maskl[T_];        // bf16 1.0/0.0

    const int qb = blockIdx.x;   // 0..15 (128 q-rows each)
    const int bh = blockIdx.y;   // 0..31
    const int b = bh >> 3;
    const int h = bh & 7;
    const int tid = threadIdx.x;  // 0..511
    const int lane = tid & 63;
    const int w = tid >> 6;       // 0..7
    const int l15 = lane & 15;
    const int lg = lane >> 4;

    const ushort* Qp = Q + (size_t)bh * T_ * DK_;
    const ushort* Kp = K + (size_t)bh * T_ * DK_;
    const ushort* Vp = Vt + (size_t)bh * DK_ * T_;

    for (int j = tid; j < 2176; j += 512) {
        int gj = qb * 128 + j;
        biasl[j] = (gj <= 4094) ? tbl[(size_t)h * TBL + gj] : 0.f;
    }
    for (int j = tid; j < T_; j += 512)
        maskl[j] = (maskw[b * T_ + j] != 0) ? 0x3F80 : 0;

    const int q0 = qb * 128 + w * 16;
    bf16x8 qf[2];
#pragma unroll
    for (int kf = 0; kf < 2; ++kf)
        qf[kf] = *(const bf16x8*)(Qp + (size_t)(q0 + l15) * DK_ + kf * 32 + lg * 8);

    f32x4 acc[4];
    float rs[4];
#pragma unroll
    for (int ni = 0; ni < 4; ++ni) acc[ni] = (f32x4){0.f, 0.f, 0.f, 0.f};
#pragma unroll
    for (int i = 0; i < 4; ++i) rs[i] = 0.f;
    __syncthreads();

    for (int kt = 0; kt < T_ / 64; ++kt) {
        // stage K and V^T tiles: 512 chunks each, 1 per thread per buffer
        {
            int r = tid >> 3;
            int scol = ((tid & 7) ^ (r & 7)) * 8;
            gload_lds16(Kp + (size_t)(kt * 64 + r) * DK_ + scol, Ks + tid * 8);
            gload_lds16(Vp + (size_t)r * T_ + kt * 64 + scol, Vs + tid * 8);
        }
        __syncthreads();

        // S = Q K^T ; P = mask * exp2(S*log2e/8 + biaspre); P -> per-wave LDS
#pragma unroll
        for (int ct = 0; ct < 4; ++ct) {
            int krow = ct * 16 + l15;
            bf16x8 kf0 = *(const bf16x8*)(Ks + krow * 64 + ((lg ^ (krow & 7)) * 8));
            bf16x8 kf1 = *(const bf16x8*)(Ks + krow * 64 + (((4 + lg) ^ (krow & 7)) * 8));
            int kg = kt * 64 + ct * 16 + l15;
            float mf = b2f(maskl[kg]);
            f32x4 S = (f32x4){0.f, 0.f, 0.f, 0.f};
            S = __builtin_amdgcn_mfma_f32_16x16x32_bf16(qf[0], kf0, S, 0, 0, 0);
            S = __builtin_amdgcn_mfma_f32_16x16x32_bf16(qf[1], kf1, S, 0, 0, 0);
            int jb = w * 16 + lg * 4 - kg + 2047;
#pragma unroll
            for (int i = 0; i < 4; ++i) {
                float pv = mf * exp2f(fmaf(S[i], 0.1803368801f, biasl[jb + i]));
                rs[i] += pv;
                int prow = lg * 4 + i;
                int pcol = ct * 16 + l15;
                Ps[w][prow * 64 + (((pcol >> 3) ^ (prow & 7)) * 8) + (pcol & 7)] = f2b(pv);
            }
        }

        // PV accumulate
#pragma unroll
        for (int kk = 0; kk < 2; ++kk) {
            bf16x8 pf = *(const bf16x8*)(Ps[w] + l15 * 64 + (((kk * 4 + lg) ^ (l15 & 7)) * 8));
#pragma unroll
            for (int ni = 0; ni < 4; ++ni) {
                int vrow = ni * 16 + l15;
                bf16x8 vf = *(const bf16x8*)(Vs + vrow * 64 + (((kk * 4 + lg) ^ (vrow & 7)) * 8));
                acc[ni] = __builtin_amdgcn_mfma_f32_16x16x32_bf16(pf, vf, acc[ni], 0, 0, 0);
            }
        }
        __syncthreads();
    }

#pragma unroll
    for (int i = 0; i < 4; ++i) {
        float v = rs[i];
        v += __shfl_xor(v, 1);
        v += __shfl_xor(v, 2);
        v += __shfl_xor(v, 4);
        v += __shfl_xor(v, 8);
        rs[i] = v;
    }

    // attention output in [b][t][h*64+d] (row-major for the final GEMM)
#pragma unroll
    for (int ni = 0; ni < 4; ++ni)
#pragma unroll
        for (int i = 0; i < 4; ++i) {
            int t = q0 + lg * 4 + i;
            int d = h * DK_ + ni * 16 + l15;
            Aout[(size_t)(b * T_ + t) * D_ + d] = f2b(acc[ni][i] / rs[i]);
        }
}

// ---------------------------------------------------------------------------
extern "C" void kernel_launch(void* const* d_in, const int* in_sizes, int n_in,
                              void* d_out, int out_size, void* d_ws, size_t ws_size,
                              hipStream_t stream) {
    const float* x   = (const float*)d_in[0];
    const void* mask = d_in[1];
    const float* Wq  = (const float*)d_in[2];
    const float* bq  = (const float*)d_in[3];
    const float* Wk  = (const float*)d_in[4];
    const float* bk  = (const float*)d_in[5];
    const float* Wv  = (const float*)d_in[6];
    const float* bv  = (const float*)d_in[7];
    const float* Wo  = (const float*)d_in[8];
    const float* bo  = (const float*)d_in[9];
    const float* E   = (const float*)d_in[11];
    float* out = (float*)d_out;   // reference output dtype is FLOAT32

    char* ws = (char*)d_ws;
    ushort* xp  = (ushort*)(ws);                 // 8 MB (xp, later attn out)
    ushort* Qw  = (ushort*)(ws + (8u << 20));    // 8 MB  [b][h][t][dk]
    ushort* Kw  = (ushort*)(ws + (16u << 20));   // 8 MB  [b][h][t][dk]
    ushort* Vw  = (ushort*)(ws + (24u << 20));   // 8 MB  [b][h][dk][t]  (V^T)
    float* tbl  = (float*)(ws + (32u << 20));               // 131 KB (256 KB reserved)
    ushort* Wc  = (ushort*)(ws + (32u << 20) + 262144);     // 2 MB
    int* maskw  = (int*)(ws + (34u << 20) + 262144);        // 32 KB
    int* flags  = (int*)(ws + (34u << 20) + 262144 + 32768);

    if (ws_size < (35u << 20)) return;

    detect_mask_kernel<<<1, 64, 0, stream>>>((const unsigned int*)mask, flags);
    mask_prep_kernel<<<(B_ * T_) / 256, 256, 0, stream>>>(mask, flags, maskw);
    bias_tbl_kernel<<<(TBL * H_ + 255) / 256, 256, 0, stream>>>(E, tbl);
    pe_kernel<<<B_ * T_, 256, 0, stream>>>(x, xp);

    dim3 gw(128, 1, 4);
    wcvt_kernel<<<gw, 256, 0, stream>>>(Wq, Wk, Wv, Wo, Wc);

    dim3 g1(D_ / 128, (B_ * T_) / 128, 3);
    gemm_bt_kernel<0><<<g1, 256, 0, stream>>>(xp, Wc, Wc + D_ * D_, Wc + 2 * D_ * D_,
                                              bq, bk, bv, Qw, Kw, Vw);

    dim3 g2(T_ / 128, B_ * H_, 1);
    attn_kernel<<<g2, 512, 0, stream>>>(Qw, Kw, Vw, maskw, tbl, xp);

    dim3 g3(D_ / 128, (B_ * T_) / 128, 1);
    gemm_bt_kernel<1><<<g3, 256, 0, stream>>>(xp, Wc + 3 * D_ * D_, Wc + 3 * D_ * D_, Wc + 3 * D_ * D_,
                                              bo, bo, bo, out, out, out);
}

// Round 11
// 220.606 us; speedup vs baseline: 1.2227x; 1.0478x over previous
//
#include <hip/hip_runtime.h>

#define B_ 4
#define T_ 2048
#define D_ 512
#define H_ 8
#define DK_ 64
#define TBL 4095

typedef __attribute__((ext_vector_type(4))) float f32x4;
typedef __attribute__((ext_vector_type(8))) short bf16x8;
typedef __attribute__((ext_vector_type(4))) int i32x4;
typedef unsigned int u32;

static __device__ __forceinline__ float b2f(ushort u) {
    union { float f; unsigned int i; } c;
    c.i = ((unsigned int)u) << 16;
    return c.f;
}

static __device__ __forceinline__ ushort f2b(float f) {
    union { float f; unsigned int i; } c;
    c.f = f;
    unsigned int i = c.i;
    unsigned int r = (i + 0x7fffu + ((i >> 16) & 1u)) >> 16;
    return (ushort)r;
}

// async global->LDS, 16 bytes/lane; LDS dest must be wave-uniform + lane*16.
static __device__ __forceinline__ void gload_lds16(const void* g, void* l) {
    __builtin_amdgcn_global_load_lds(
        (const __attribute__((address_space(1))) u32*)g,
        (__attribute__((address_space(3))) u32*)(u32)(unsigned long long)l,
        16, 0, 0);
}

// ---------------------------------------------------------------------------
// mask width detection: flags[0] = 0 (4-byte int/f32), 1 (1-byte), 2 (2-byte)
__global__ __launch_bounds__(64) void detect_mask_kernel(const unsigned int* __restrict__ mask,
                                                         int* __restrict__ flags) {
    int lane = threadIdx.x;
    int c2 = 0, c1 = 0;
    for (int i = lane; i < 512; i += 64) {
        unsigned int v = mask[i];
        c2 += (v == 0x3F803F80u || v == 0x00010001u) ? 1 : 0;
        c1 += (v == 0x01010101u) ? 1 : 0;
    }
#pragma unroll
    for (int m = 1; m < 64; m <<= 1) {
        c2 += __shfl_xor(c2, m);
        c1 += __shfl_xor(c1, m);
    }
    if (lane == 0) flags[0] = (c2 > 8) ? 2 : ((c1 > 8) ? 1 : 0);
}

__global__ __launch_bounds__(256) void mask_prep_kernel(const void* __restrict__ mask,
                                                        const int* __restrict__ flags,
                                                        int* __restrict__ maskw) {
    int j = blockIdx.x * 256 + threadIdx.x;   // 0..8191
    int fm = flags[0];
    int v;
    if (fm == 2)      v = (((const ushort*)mask)[j] != 0);
    else if (fm == 1) v = (((const unsigned char*)mask)[j] != 0);
    else              v = (((const int*)mask)[j] != 0);
    maskw[j] = v;
}

// ---------------------------------------------------------------------------
// weights f32 -> bf16 (4 weights, z selects)
__global__ __launch_bounds__(256) void wcvt_kernel(
    const float* __restrict__ W0, const float* __restrict__ W1,
    const float* __restrict__ W2, const float* __restrict__ W3,
    ushort* __restrict__ Wc) {
    const int z = blockIdx.z;
    const float* Ws = (z == 0) ? W0 : ((z == 1) ? W1 : ((z == 2) ? W2 : W3));
    int idx = blockIdx.x * 256 + threadIdx.x;    // 0..32767, 8 elements each
    const float* wf = Ws + idx * 8;
    f32x4 a = *(const f32x4*)(wf);
    f32x4 c = *(const f32x4*)(wf + 4);
    union { ushort u[8]; i32x4 v; } o;
#pragma unroll
    for (int j = 0; j < 4; ++j) { o.u[j] = f2b(a[j]); o.u[4 + j] = f2b(c[j]); }
    *(i32x4*)(Wc + (size_t)z * (D_ * D_) + idx * 8) = o.v;
}

// ---------------------------------------------------------------------------
// xp = bf16(x + sinusoidal_pe(t, d)); one thread per (row, dim-pair).
__global__ __launch_bounds__(256) void pe_kernel(const float* __restrict__ x,
                                                 ushort* __restrict__ xp) {
    int idx = blockIdx.x * 256 + threadIdx.x;
    int i = idx & 255;        // pair index (dims 2i, 2i+1)
    int row = idx >> 8;       // b*T + t
    int t = row & (T_ - 1);
    float div = __expf((float)i * -0.035977892f);   // exp(-(2i)*ln(1e4)/512)
    float ang = (float)t * div;
    float s = sinf(ang);
    float c = cosf(ang);
    float2 v = ((const float2*)x)[row * 256 + i];
    unsigned int o = (unsigned int)f2b(v.x + s) | ((unsigned int)f2b(v.y + c) << 16);
    *(unsigned int*)(xp + (size_t)row * D_ + 2 * i) = o;
}

// ---------------------------------------------------------------------------
// antisymmetric rel-pos bias table, PRE-SCALED by log2(e):
// tbl[h][j] = log2e * 0.5 * (E[j,h] - E[4094-j,h])
__global__ __launch_bounds__(256) void bias_tbl_kernel(const float* __restrict__ E,
                                                       float* __restrict__ tbl) {
    int idx = blockIdx.x * 256 + threadIdx.x;
    if (idx >= TBL * H_) return;
    int h = idx & 7;
    int j = idx >> 3;
    tbl[(size_t)h * TBL + j] =
        0.72134752044f * (E[(size_t)j * H_ + h] - E[(size_t)(4094 - j) * H_ + h]);
}

// ---------------------------------------------------------------------------
// GEMM: C[m][n] = sum_k A[m][k]*W[n][k] + bias[n], bf16 in, f32 acc.
// 128x128 tile, 4 waves, BK=64, T2 XOR-swizzled LDS.
// OUTMODE 0: bf16 out; z 0/1 (Q,K) -> [b][h][t][dk]; z 2 (V) -> [b][h][dk][t]
//            via LDS-transposed coalesced epilogue.
// OUTMODE 1: f32 out row-major (final output).
template <int OUTMODE>
__global__ __launch_bounds__(256) void gemm_bt_kernel(
    const ushort* __restrict__ A,
    const ushort* __restrict__ W0, const ushort* __restrict__ W1, const ushort* __restrict__ W2,
    const float* __restrict__ bias0, const float* __restrict__ bias1, const float* __restrict__ bias2,
    void* __restrict__ O0, void* __restrict__ O1, void* __restrict__ O2) {
    __shared__ ushort SBUF[128 * 136];          // staging (As|Bs = 32KB) + V^T transpose
    ushort* As = SBUF;                          // 128*64
    ushort* Bs = SBUF + 128 * 64;               // 128*64

    const int z = blockIdx.z;
    const ushort* Wp = (z == 0) ? W0 : ((z == 1) ? W1 : W2);
    const float* bp = (z == 0) ? bias0 : ((z == 1) ? bias1 : bias2);
    void* Op = (z == 0) ? O0 : ((z == 1) ? O1 : O2);

    const int n0 = blockIdx.x * 128;
    const int m0 = blockIdx.y * 128;
    const int tid = threadIdx.x;
    const int lane = tid & 63;
    const int w = tid >> 6;
    const int wr = (w >> 1) * 64;
    const int wc = (w & 1) * 64;
    const int l15 = lane & 15;
    const int lg = lane >> 4;

    f32x4 acc[4][4];
#pragma unroll
    for (int mi = 0; mi < 4; ++mi)
#pragma unroll
        for (int ni = 0; ni < 4; ++ni)
            acc[mi][ni] = (f32x4){0.f, 0.f, 0.f, 0.f};

    for (int kt = 0; kt < D_ / 64; ++kt) {   // 8 K-steps
#pragma unroll
        for (int p = 0; p < 4; ++p) {
            int c = tid + p * 256;           // 0..1023 chunks of 16B
            int r = c >> 3;
            int scol = ((c & 7) ^ (r & 7)) * 8;   // inverse-swizzled source col
            gload_lds16(A  + (size_t)(m0 + r) * D_ + kt * 64 + scol, As + c * 8);
            gload_lds16(Wp + (size_t)(n0 + r) * D_ + kt * 64 + scol, Bs + c * 8);
        }
        __syncthreads();

#pragma unroll
        for (int ks = 0; ks < 2; ++ks) {
            bf16x8 af[4], bfr[4];
#pragma unroll
            for (int mi = 0; mi < 4; ++mi)
                af[mi] = *(const bf16x8*)(As + (wr + mi * 16 + l15) * 64 +
                                          (((ks * 4 + lg) ^ (l15 & 7)) * 8));
#pragma unroll
            for (int ni = 0; ni < 4; ++ni)
                bfr[ni] = *(const bf16x8*)(Bs + (wc + ni * 16 + l15) * 64 +
                                           (((ks * 4 + lg) ^ (l15 & 7)) * 8));
#pragma unroll
            for (int mi = 0; mi < 4; ++mi)
#pragma unroll
                for (int ni = 0; ni < 4; ++ni)
                    acc[mi][ni] = __builtin_amdgcn_mfma_f32_16x16x32_bf16(af[mi], bfr[ni], acc[mi][ni], 0, 0, 0);
        }
        __syncthreads();
    }

    if (OUTMODE == 0 && z == 2) {
        // V^T epilogue: acc -> LDS [n_local][m_local] (pad 136), then coalesced
        // row-major [b][h][dk][t] stores (256B contiguous per dk-row).
#pragma unroll
        for (int ni = 0; ni < 4; ++ni) {
            int nl = wc + ni * 16 + l15;
            float bv = bp[n0 + nl];
#pragma unroll
            for (int mi = 0; mi < 4; ++mi)
#pragma unroll
                for (int i = 0; i < 4; ++i)
                    SBUF[nl * 136 + wr + mi * 16 + lg * 4 + i] = f2b(acc[mi][ni][i] + bv);
        }
        __syncthreads();
        const int bb = m0 >> 11;
        const int t0 = m0 & 2047;
#pragma unroll
        for (int it = 0; it < 8; ++it) {
            int cc = it * 256 + tid;       // 0..2047
            int nl = cc >> 4;              // 0..127
            int mc = cc & 15;              // 16B chunk in m
            int n = n0 + nl;
            size_t off = ((size_t)(bb * H_ + (n >> 6)) * DK_ + (n & 63)) * T_ + t0 + mc * 8;
            *(i32x4*)((ushort*)Op + off) = *(const i32x4*)(SBUF + nl * 136 + mc * 8);
        }
    } else {
#pragma unroll
        for (int ni = 0; ni < 4; ++ni) {
            int n = n0 + wc + ni * 16 + l15;
            float bv = bp[n];
#pragma unroll
            for (int mi = 0; mi < 4; ++mi) {
#pragma unroll
                for (int i = 0; i < 4; ++i) {
                    int m = m0 + wr + mi * 16 + lg * 4 + i;
                    float v = acc[mi][ni][i] + bv;
                    if (OUTMODE == 0) {
                        int b = m >> 11;
                        int t = m & 2047;
                        ((ushort*)Op)[(((size_t)(b * H_ + (n >> 6)) * T_ + t) << 6) + (n & 63)] = f2b(v);
                    } else {
                        ((float*)Op)[(size_t)m * D_ + n] = v;   // f32 final output
                    }
                }
            }
        }
    }
}

// ---------------------------------------------------------------------------
// fused attention: 8 waves x 16 q-rows = 128 q-rows/block. Swapped QK^T
// (mfma(K,Q)) so P packs via cvt_pk + b32 stores. XCD-local block map.
// P LDS layout (per wave, 16 rows x 128B): byte = q*128 + ((slot16^(q&7))<<4)
// + within16 — same XOR pattern as the GEMM frag reads (measured 0-conflict).
__global__ __launch_bounds__(512) void attn_kernel(
    const ushort* __restrict__ Q, const ushort* __restrict__ K, const ushort* __restrict__ Vt,
    const int* __restrict__ maskw, const float* __restrict__ tbl,
    ushort* __restrict__ Aout) {
    __shared__ ushort Ks[64 * 64];      // chunk (r,s) holds K[key=r] col-chunk s^(r&7)
    __shared__ ushort Vs[64 * 64];      // chunk (r,s) holds V^T[dk=r] key-chunk s^(r&7)
    __shared__ ushort Ps[8][16 * 64];   // per-wave P [q][k] slot-swizzled
    __shared__ float biasl[2176];       // pre-scaled by log2e
    __shared__ float maskf[T_];         // additive: 0 or -1e5

    // XCD-locality map: blocks with the same (id&7) share 4 bh values
    const int id = blockIdx.x;          // 0..511
    const int j1 = id >> 3;             // 0..63
    const int bh = (id & 7) * 4 + (j1 >> 4);
    const int qb = j1 & 15;
    const int b = bh >> 3;
    const int h = bh & 7;
    const int tid = threadIdx.x;  // 0..511
    const int lane = tid & 63;
    const int w = tid >> 6;       // 0..7
    const int l15 = lane & 15;
    const int lg = lane >> 4;

    const ushort* Qp = Q + (size_t)bh * T_ * DK_;
    const ushort* Kp = K + (size_t)bh * T_ * DK_;
    const ushort* Vp = Vt + (size_t)bh * DK_ * T_;

    for (int j = tid; j < 2176; j += 512) {
        int gj = qb * 128 + j;
        biasl[j] = (gj <= 4094) ? tbl[(size_t)h * TBL + gj] : 0.f;
    }
    for (int j = tid; j < T_; j += 512)
        maskf[j] = (maskw[b * T_ + j] != 0) ? 0.f : -100000.f;

    const int q0 = qb * 128 + w * 16;
    bf16x8 qf[2];
#pragma unroll
    for (int kf = 0; kf < 2; ++kf)
        qf[kf] = *(const bf16x8*)(Qp + (size_t)(q0 + l15) * DK_ + kf * 32 + lg * 8);

    f32x4 acc[4];
    float rs = 0.f;
#pragma unroll
    for (int ni = 0; ni < 4; ++ni) acc[ni] = (f32x4){0.f, 0.f, 0.f, 0.f};
    __syncthreads();

    char* PsB = (char*)Ps[w];
    const u32 prow = (u32)(l15 * 128);
    const u32 pxor = (u32)(l15 & 7);

    for (int kt = 0; kt < T_ / 64; ++kt) {
        // stage K and V^T tiles: 512 chunks each, 1 per thread per buffer
        {
            int r = tid >> 3;
            int scol = ((tid & 7) ^ (r & 7)) * 8;
            gload_lds16(Kp + (size_t)(kt * 64 + r) * DK_ + scol, Ks + tid * 8);
            gload_lds16(Vp + (size_t)r * T_ + kt * 64 + scol, Vs + tid * 8);
        }
        __syncthreads();

        // S^T = K Q^T (row=key, col=q); P = exp2(S*c + bias + maskadd)
#pragma unroll
        for (int ct = 0; ct < 4; ++ct) {
            int krow = ct * 16 + l15;
            bf16x8 kf0 = *(const bf16x8*)(Ks + krow * 64 + ((lg ^ (krow & 7)) * 8));
            bf16x8 kf1 = *(const bf16x8*)(Ks + krow * 64 + (((4 + lg) ^ (krow & 7)) * 8));
            f32x4 S = (f32x4){0.f, 0.f, 0.f, 0.f};
            S = __builtin_amdgcn_mfma_f32_16x16x32_bf16(kf0, qf[0], S, 0, 0, 0);
            S = __builtin_amdgcn_mfma_f32_16x16x32_bf16(kf1, qf[1], S, 0, 0, 0);
            int k0 = ct * 16 + lg * 4;                 // local key base for this lane
            f32x4 mv = *(const f32x4*)(maskf + kt * 64 + k0);
            int jb0 = w * 16 + l15 - (kt * 64 + k0) + 2047;
            float p0 = exp2f(fmaf(S[0], 0.1803368801f, biasl[jb0]     + mv[0]));
            float p1 = exp2f(fmaf(S[1], 0.1803368801f, biasl[jb0 - 1] + mv[1]));
            float p2 = exp2f(fmaf(S[2], 0.1803368801f, biasl[jb0 - 2] + mv[2]));
            float p3 = exp2f(fmaf(S[3], 0.1803368801f, biasl[jb0 - 3] + mv[3]));
            rs += (p0 + p1) + (p2 + p3);
            u32 pk0, pk1;
            asm("v_cvt_pk_bf16_f32 %0, %1, %2" : "=v"(pk0) : "v"(p0), "v"(p1));
            asm("v_cvt_pk_bf16_f32 %0, %1, %2" : "=v"(pk1) : "v"(p2), "v"(p3));
            // slot16 = (k0*2)>>4 = ct*2 + (lg>>1); within16 = (lg&1)*8
            u32 slot16 = (u32)(ct * 2 + (lg >> 1));
            u32 byte0 = prow + ((slot16 ^ pxor) << 4) + (u32)((lg & 1) * 8);
            *(u32*)(PsB + byte0) = pk0;
            *(u32*)(PsB + byte0 + 4) = pk1;
        }

        // PV accumulate: O[q][d] += P[q][k] V[k][d]
#pragma unroll
        for (int kk = 0; kk < 2; ++kk) {
            bf16x8 pf = *(const bf16x8*)(PsB + prow + ((((u32)(kk * 4 + lg)) ^ pxor) << 4));
#pragma unroll
            for (int ni = 0; ni < 4; ++ni) {
                int vrow = ni * 16 + l15;
                bf16x8 vf = *(const bf16x8*)(Vs + vrow * 64 + (((kk * 4 + lg) ^ (vrow & 7)) * 8));
                acc[ni] = __builtin_amdgcn_mfma_f32_16x16x32_bf16(pf, vf, acc[ni], 0, 0, 0);
            }
        }
        __syncthreads();
    }

    // rowsum: lane's rs covers q=l15 over its lg key slices; fold lg groups
    rs += __shfl_xor(rs, 16);
    rs += __shfl_xor(rs, 32);
    // redistribute: output lanes need rs for q-row (lg*4+i); bounce via LDS
    float* rsl = (float*)Ks;     // 16 floats per wave (Ks dead after loop)
    if (lane < 16) rsl[w * 16 + lane] = rs;
    __syncthreads();

    // attention output in [b][t][h*64+d] (row-major for the final GEMM)
#pragma unroll
    for (int ni = 0; ni < 4; ++ni)
#pragma unroll
        for (int i = 0; i < 4; ++i) {
            int t = q0 + lg * 4 + i;
            int d = h * DK_ + ni * 16 + l15;
            Aout[(size_t)(b * T_ + t) * D_ + d] = f2b(acc[ni][i] / rsl[w * 16 + lg * 4 + i]);
        }
}

// ---------------------------------------------------------------------------
extern "C" void kernel_launch(void* const* d_in, const int* in_sizes, int n_in,
                              void* d_out, int out_size, void* d_ws, size_t ws_size,
                              hipStream_t stream) {
    const float* x   = (const float*)d_in[0];
    const void* mask = d_in[1];
    const float* Wq  = (const float*)d_in[2];
    const float* bq  = (const float*)d_in[3];
    const float* Wk  = (const float*)d_in[4];
    const float* bk  = (const float*)d_in[5];
    const float* Wv  = (const float*)d_in[6];
    const float* bv  = (const float*)d_in[7];
    const float* Wo  = (const float*)d_in[8];
    const float* bo  = (const float*)d_in[9];
    const float* E   = (const float*)d_in[11];
    float* out = (float*)d_out;   // reference output dtype is FLOAT32

    char* ws = (char*)d_ws;
    ushort* xp  = (ushort*)(ws);                 // 8 MB (xp, later attn out)
    ushort* Qw  = (ushort*)(ws + (8u << 20));    // 8 MB  [b][h][t][dk]
    ushort* Kw  = (ushort*)(ws + (16u << 20));   // 8 MB  [b][h][t][dk]
    ushort* Vw  = (ushort*)(ws + (24u << 20));   // 8 MB  [b][h][dk][t]  (V^T)
    float* tbl  = (float*)(ws + (32u << 20));               // 131 KB (256 KB reserved)
    ushort* Wc  = (ushort*)(ws + (32u << 20) + 262144);     // 2 MB
    int* maskw  = (int*)(ws + (34u << 20) + 262144);        // 32 KB
    int* flags  = (int*)(ws + (34u << 20) + 262144 + 32768);

    if (ws_size < (35u << 20)) return;

    detect_mask_kernel<<<1, 64, 0, stream>>>((const unsigned int*)mask, flags);
    mask_prep_kernel<<<(B_ * T_) / 256, 256, 0, stream>>>(mask, flags, maskw);
    bias_tbl_kernel<<<(TBL * H_ + 255) / 256, 256, 0, stream>>>(E, tbl);
    pe_kernel<<<B_ * T_, 256, 0, stream>>>(x, xp);

    dim3 gw(128, 1, 4);
    wcvt_kernel<<<gw, 256, 0, stream>>>(Wq, Wk, Wv, Wo, Wc);

    dim3 g1(D_ / 128, (B_ * T_) / 128, 3);
    gemm_bt_kernel<0><<<g1, 256, 0, stream>>>(xp, Wc, Wc + D_ * D_, Wc + 2 * D_ * D_,
                                              bq, bk, bv, Qw, Kw, Vw);

    attn_kernel<<<512, 512, 0, stream>>>(Qw, Kw, Vw, maskw, tbl, xp);

    dim3 g3(D_ / 128, (B_ * T_) / 128, 1);
    gemm_bt_kernel<1><<<g3, 256, 0, stream>>>(xp, Wc + 3 * D_ * D_, Wc + 3 * D_ * D_, Wc + 3 * D_ * D_,
                                              bo, bo, bo, out, out, out);
}